// Round 5
// baseline (236.606 us; speedup 1.0000x reference)
//
#include <hip/hip_runtime.h>
#include <math.h>

#define DIM   1024
#define HEADS 16
#define HDIM  64
#define SEQ   1024
#define BATCH 8
// SCALE * log2(e): Q is pre-scaled by this in the QKV epilogue so attention
// can use exp2 directly: exp2(s*SCALE*log2e) == exp(s*SCALE).
#define QSCALE 0.1803368801111204f
#define LDH   72       // Q LDS row stride in bf16 (64 + 8 pad)
#define ABM   128      // attention query tile (32 queries per wave)

typedef __attribute__((ext_vector_type(8)))  short          short8_t;   // MFMA bf16 frag
typedef __attribute__((ext_vector_type(8)))  unsigned short ushort8_t;
typedef __attribute__((ext_vector_type(4)))  unsigned short ushort4_t;
typedef __attribute__((ext_vector_type(2)))  unsigned int   uintx2;
typedef __attribute__((ext_vector_type(4)))  unsigned int   uintx4;
typedef __attribute__((ext_vector_type(4)))  float          floatx4;
typedef __attribute__((ext_vector_type(16))) float          floatx16;

__device__ __forceinline__ unsigned short f2bf(float f) {
    unsigned u = __float_as_uint(f);
    u += 0x7fffu + ((u >> 16) & 1u);      // round-to-nearest-even
    return (unsigned short)(u >> 16);
}
__device__ __forceinline__ unsigned rnd_bf(float f) {  // RNE-rounded, bf16 in bits 31:16
    unsigned u = __float_as_uint(f);
    return u + 0x7fffu + ((u >> 16) & 1u);
}
__device__ __forceinline__ float fast_exp2(float x) {
#if __has_builtin(__builtin_amdgcn_exp2f)
    return __builtin_amdgcn_exp2f(x);
#else
    return exp2f(x);
#endif
}
__device__ __forceinline__ void glds16(const unsigned short* g, unsigned short* l) {
    __builtin_amdgcn_global_load_lds(
        (const __attribute__((address_space(1))) void*)g,
        (__attribute__((address_space(3))) void*)l, 16, 0, 0);
}

// 2-D XCD-chunked bijective block swizzle. Dispatch-linear id lin is assigned
// XCD lin&7 (round-robin). Each XCD owns a (gridDim.x/4) x (gridDim.y/2)
// chunk of the tile grid, traversed bx-fastest, so the per-XCD B-panel set
// stays L2-resident (QKV: 12 panels x 256KB = 3MB < 4MB L2/XCD).
// Requires gridDim.x%4==0, gridDim.y%2==0.
__device__ __forceinline__ void xcd_swizzle(int& bx, int& by) {
    const int lin = blockIdx.y * gridDim.x + blockIdx.x;
    const int cw  = gridDim.x >> 2;           // chunk width  (bx per XCD)
    const int chh = gridDim.y >> 1;           // chunk height (by per XCD)
    const int i   = lin >> 3;
    bx = (lin & 3) * cw + i / chh;
    by = ((lin >> 2) & 1) * chh + i % chh;
}

// ---------------------------------------------------------------------------
// Fused fp32 -> bf16 cast of x, W_qkv, W_proj in one launch (8 elems/thread).
// ---------------------------------------------------------------------------
__global__ __launch_bounds__(256) void cvt_bf16_all(const float* __restrict__ x,
                                                    const float* __restrict__ wqkv,
                                                    const float* __restrict__ wproj,
                                                    unsigned short* __restrict__ x_o,
                                                    unsigned short* __restrict__ wqkv_o,
                                                    unsigned short* __restrict__ wproj_o) {
    const int N8_X = BATCH * SEQ * DIM / 8;         // 1048576
    const int N8_WQ = 3 * DIM * DIM / 8;            // 393216
    const int N8_WP = DIM * DIM / 8;                // 131072
    int i = blockIdx.x * 256 + threadIdx.x;
    const float* in;
    unsigned short* out;
    if (i < N8_X)               { in = x;     out = x_o; }
    else if (i < N8_X + N8_WQ)  { i -= N8_X;  in = wqkv; out = wqkv_o; }
    else                        { i -= N8_X + N8_WQ;
                                  if (i >= N8_WP) return;
                                  in = wproj; out = wproj_o; }
    const float4* p = (const float4*)in + (size_t)i * 2;
    float4 a = p[0], b = p[1];
    ushort8_t u;
    u[0] = f2bf(a.x); u[1] = f2bf(a.y); u[2] = f2bf(a.z); u[3] = f2bf(a.w);
    u[4] = f2bf(b.x); u[5] = f2bf(b.y); u[6] = f2bf(b.z); u[7] = f2bf(b.w);
    ((ushort8_t*)out)[i] = u;
}

// ---------------------------------------------------------------------------
// C[M,N] = A[M,K] @ B[N,K]^T, bf16 in, fp32 MFMA accumulate.  128^2 tile,
// BK=64, 2-barrier glds, 8-chunk xor swizzle, 32x32x16 MFMA (2x2 accs/wave).
// This is the round-0 proven structure (QKV measured 69.0 us / 746 TF); the
// 256^2 8-phase experiments (r1-r3) were all neutral-to-worse on this shape
// (short K=1024 + 1-block/CU grid tail), so both QKV and proj use this.
// A/B frag: [m=lane&31][k=(lane>>5)*8+j]; C/D: col=lane&31,
// row=(reg&3)+8*(reg>>2)+4*(lane>>5)  [measured m74/m101].
// MODE 0: fp32 out + bias. MODE 2: QKV split — cols<1024 -> Q bf16 *QSCALE;
// 1024..2047 -> K bf16; >=2048 -> V TRANSPOSED to vt[b][h][d][token].
// ---------------------------------------------------------------------------
template<int MODE>
__global__ __launch_bounds__(256) void gemm_nt_mfma(const unsigned short* __restrict__ A,
                                                    const unsigned short* __restrict__ B,
                                                    const float* __restrict__ bias,
                                                    void* __restrict__ Cout,
                                                    unsigned short* __restrict__ vt,
                                                    int M, int N, int K) {
    __shared__ __align__(16) unsigned short As[128 * 64];   // 16 KB
    __shared__ __align__(16) unsigned short Bs[128 * 64];   // 16 KB

    const int tid  = threadIdx.x;
    const int lane = tid & 63;
    const int wave = tid >> 6;
    const int wm = (wave >> 1) * 64;
    const int wn = (wave & 1) * 64;
    int bxi, byi;
    xcd_swizzle(bxi, byi);
    const size_t brow = (size_t)bxi * 128;
    const size_t bcol = (size_t)byi * 128;

    const int srow   = lane >> 3;                 // 0..7
    const int schunk = (lane & 7) ^ srow;         // xor-swizzled global chunk
    const unsigned short* gA = A + (brow + wave * 8 + srow) * (size_t)K + schunk * 8;
    const unsigned short* gB = B + (bcol + wave * 8 + srow) * (size_t)K + schunk * 8;
    unsigned short* lA = &As[wave * 512 + lane * 8];
    unsigned short* lB = &Bs[wave * 512 + lane * 8];

    floatx16 acc[2][2];
    #pragma unroll
    for (int i = 0; i < 2; i++)
        #pragma unroll
        for (int j = 0; j < 2; j++)
            #pragma unroll
            for (int r = 0; r < 16; r++) acc[i][j][r] = 0.f;

    const int c32  = lane & 31;   // frag row (m for A, n for B)
    const int half = lane >> 5;   // k-half selector
    const int xr   = c32 & 7;     // row xor for swizzled reads

    for (int k0 = 0; k0 < K; k0 += 64) {
        __syncthreads();
        #pragma unroll
        for (int r = 0; r < 4; r++) {
            glds16(gA + (size_t)r * 32 * K + k0, lA + r * 2048);
            glds16(gB + (size_t)r * 32 * K + k0, lB + r * 2048);
        }
        __syncthreads();

        #pragma unroll
        for (int s = 0; s < 4; s++) {   // 4 k-steps of 16
            const int ch = ((s * 2 + half) ^ xr) * 8;   // swizzled chunk offset
            short8_t a0 = *(const short8_t*)&As[(wm + c32) * 64 + ch];
            short8_t a1 = *(const short8_t*)&As[(wm + 32 + c32) * 64 + ch];
            short8_t b0 = *(const short8_t*)&Bs[(wn + c32) * 64 + ch];
            short8_t b1 = *(const short8_t*)&Bs[(wn + 32 + c32) * 64 + ch];
            acc[0][0] = __builtin_amdgcn_mfma_f32_32x32x16_bf16(a0, b0, acc[0][0], 0, 0, 0);
            acc[0][1] = __builtin_amdgcn_mfma_f32_32x32x16_bf16(a0, b1, acc[0][1], 0, 0, 0);
            acc[1][0] = __builtin_amdgcn_mfma_f32_32x32x16_bf16(a1, b0, acc[1][0], 0, 0, 0);
            acc[1][1] = __builtin_amdgcn_mfma_f32_32x32x16_bf16(a1, b1, acc[1][1], 0, 0, 0);
        }
    }

    // C/D: col = c32, row = (r&3) + 8*(r>>2) + 4*half
    if (MODE == 0) {
        #pragma unroll
        for (int mi = 0; mi < 2; mi++)
            #pragma unroll
            for (int ni = 0; ni < 2; ni++) {
                const size_t col = bcol + wn + ni * 32 + c32;
                const float bv = bias[col];
                #pragma unroll
                for (int r = 0; r < 16; r++) {
                    const size_t row = brow + wm + mi * 32 + (r & 3) + 8 * (r >> 2) + 4 * half;
                    ((float*)Cout)[row * N + col] = acc[mi][ni][r] + bv;
                }
            }
    } else {  // MODE 2: QKV split epilogue
        if (bcol < 2048) {
            const float sc = (bcol < 1024) ? QSCALE : 1.0f;  // pre-scale Q
            unsigned short* qk = (unsigned short*)Cout;
            #pragma unroll
            for (int mi = 0; mi < 2; mi++)
                #pragma unroll
                for (int ni = 0; ni < 2; ni++) {
                    const size_t col = bcol + wn + ni * 32 + c32;
                    #pragma unroll
                    for (int r = 0; r < 16; r++) {
                        const size_t row = brow + wm + mi * 32 + (r & 3) + 8 * (r >> 2) + 4 * half;
                        qk[row * 2048 + col] = f2bf(acc[mi][ni][r] * sc);
                    }
                }
        } else {
            #pragma unroll
            for (int mi = 0; mi < 2; mi++)
                #pragma unroll
                for (int ni = 0; ni < 2; ni++) {
                    const int dall = (int)(bcol + wn + ni * 32 + c32) - 2048;
                    const int h = dall >> 6, d = dall & 63;
                    #pragma unroll
                    for (int rg = 0; rg < 4; rg++) {   // reg-quad = 4 consecutive rows
                        const size_t row0 = brow + wm + mi * 32 + rg * 8 + 4 * half;
                        const size_t bb = row0 >> 10;
                        const int n0 = (int)(row0 & 1023);
                        ushort4_t o;
                        #pragma unroll
                        for (int q = 0; q < 4; q++) o[q] = f2bf(acc[mi][ni][rg * 4 + q]);
                        *(ushort4_t*)&vt[(((size_t)bb * HEADS + h) * HDIM + d) * SEQ + n0] = o;
                    }
                }
        }
    }
}

// ---------------------------------------------------------------------------
// MFMA flash attention, S^T formulation with 32x32x16 MFMA. ABM=128, 4 waves;
// wave w owns queries w*32 + (lane&31). Per 64-key tile (dbuf LDS, one
// barrier, register prefetch after the barrier):
//   S^T = K Q^T via 8 mfma_32x32x16 (2 key-row-tiles x 4 k-steps).
//   C-layout: col = query (lane&31) -> each lane owns ONE query; rows = keys
//   (r&3)+8(r>>2)+4*half (+t*32): lanes l and l^32 hold complementary 4-key
//   sub-halves of every 8-key block -> lsum reduction is one shfl_xor(32).
//   p = exp2(s) (Q pre-scaled; no max tracking).
//   P -> PV A-frags ENTIRELY IN REGISTERS (T12): pack quads to bf16 words
//   w0[b],w1[b] (b = 4t+rg = 8-key block; lanes<32 hold lo-pairs, lanes>=32
//   hi-pairs), then ap32 words via v_permlane32_swap (swaps hi 32 lanes of
//   operand0 with lo 32 lanes of operand1):
//     (ap32[0], ap32[2]) = swap(w0[2s], w0[2s+1])
//     (ap32[1], ap32[3]) = swap(w1[2s], w1[2s+1])
//   -> half0 lanes get block 2s, half1 lanes block 2s+1, exactly the
//   A-frag's k=(lane>>5)*8+j layout. Replaces the former per-tile LDS P
//   round-trip (8 ds_write_b64 + 4 ds_read_b128 + in-order DS latency)
//   with 8 VALU-rate permlanes.
//   PV: O[query][dim] += P V^T, B = V^T[dim][key] frags from LDS.
// Grid = (b*HEADS+h, qt): XCD-local K/V.
// ---------------------------------------------------------------------------
__global__ __launch_bounds__(256) void attn_mfma(const unsigned short* __restrict__ qk,
                                                 const unsigned short* __restrict__ vt,
                                                 unsigned short* __restrict__ aout) {
    const int bh = blockIdx.x;           // b*HEADS + h
    const int qt = blockIdx.y;           // 0..7
    const int h  = bh & 15;
    const int b  = bh >> 4;
    const int tid  = threadIdx.x;
    const int lane = tid & 63;
    const int wave = tid >> 6;
    const int c32  = lane & 31;   // query index within wave's 32
    const int half = lane >> 5;   // k-half / key-row-half selector

    __shared__ __align__(16) unsigned short Qs[ABM * LDH];      // Q staging
    __shared__ __align__(16) unsigned short Ks[2][64 * 64];     // swizzled
    __shared__ __align__(16) unsigned short Vs[2][64 * 64];     // V^T, swizzled
    __shared__ float scr[4][32];

    const int sr = tid >> 2;   // K/V staging row 0..63
    const int sq = tid & 3;    // two 16B chunks: 2sq, 2sq+1 (pre-swizzle)
    const int sx = sr & 7;     // staging row xor
    const unsigned short* ksrc0 =
        qk + ((size_t)(b * SEQ + sr)) * 2048 + DIM + h * HDIM + sq * 16;
    const unsigned short* vsrc0 =
        vt + (((size_t)(b * HEADS + h)) * HDIM + sr) * SEQ + sq * 16;
    // swizzled LDS staging offsets (bf16 units): row*64 + (chunk^xr)*8
    const int kvo0 = sr * 64 + (((sq * 2)     ^ sx) * 8);
    const int kvo1 = sr * 64 + (((sq * 2 + 1) ^ sx) * 8);

    // prefetch K/V tile 0 into registers
    ushort8_t ck0 = *(const ushort8_t*)ksrc0;
    ushort8_t ck1 = *(const ushort8_t*)(ksrc0 + 8);
    ushort8_t cv0 = *(const ushort8_t*)vsrc0;
    ushort8_t cv1 = *(const ushort8_t*)(vsrc0 + 8);

    // stage Q tile: 128 rows x 64 cols; thread -> row tid>>1, 32-col half
    {
        const int r  = tid >> 1;
        const int c0 = (tid & 1) * 32;
        const unsigned short* src =
            qk + ((size_t)(b * SEQ + qt * ABM + r)) * 2048 + h * HDIM + c0;
        unsigned short* dst = &Qs[r * LDH + c0];
        *(ushort8_t*)(dst)      = *(const ushort8_t*)(src);
        *(ushort8_t*)(dst + 8)  = *(const ushort8_t*)(src + 8);
        *(ushort8_t*)(dst + 16) = *(const ushort8_t*)(src + 16);
        *(ushort8_t*)(dst + 24) = *(const ushort8_t*)(src + 24);
    }
    __syncthreads();

    // Q B-fragments (4 k-steps of 16 dims), register-resident for the kernel
    short8_t bq[4];
    #pragma unroll
    for (int s = 0; s < 4; s++)
        bq[s] = *(const short8_t*)&Qs[(wave * 32 + c32) * LDH + s * 16 + half * 8];

    floatx16 O[2];   // O[dt]: rows = quad queries, col dim = dt*32 + c32
    #pragma unroll
    for (int dt = 0; dt < 2; dt++)
        #pragma unroll
        for (int r = 0; r < 16; r++) O[dt][r] = 0.f;
    float lsum = 0.f;

    const int fxr = c32 & 7;   // frag-read row xor (rows step by 32)

    for (int kt = 0; kt < SEQ / 64; kt++) {
        const int cur = kt & 1;
        // write prefetched K/V into buf[cur] (vmcnt wait lands here, a full
        // MFMA phase after the loads were issued)
        *(ushort8_t*)&Ks[cur][kvo0] = ck0;
        *(ushort8_t*)&Ks[cur][kvo1] = ck1;
        *(ushort8_t*)&Vs[cur][kvo0] = cv0;
        *(ushort8_t*)&Vs[cur][kvo1] = cv1;
        __syncthreads();   // ONE barrier per tile
        // issue next tile's global loads AFTER the barrier
        if (kt + 1 < SEQ / 64) {
            const unsigned short* ks = ksrc0 + (size_t)(kt + 1) * 64 * 2048;
            const unsigned short* vs = vsrc0 + (kt + 1) * 64;
            ck0 = *(const ushort8_t*)ks;
            ck1 = *(const ushort8_t*)(ks + 8);
            cv0 = *(const ushort8_t*)vs;
            cv1 = *(const ushort8_t*)(vs + 8);
        }

        // S^T = K Q^T : 2 key-row-tiles x 4 k-steps of 32x32x16
        floatx16 S[2];
        #pragma unroll
        for (int t = 0; t < 2; t++)
            #pragma unroll
            for (int r = 0; r < 16; r++) S[t][r] = 0.f;
        #pragma unroll
        for (int t = 0; t < 2; t++)
            #pragma unroll
            for (int s = 0; s < 4; s++) {
                const int slot = ((s * 2 + half) ^ fxr) * 8;
                short8_t ak = *(const short8_t*)&Ks[cur][(t * 32 + c32) * 64 + slot];
                S[t] = __builtin_amdgcn_mfma_f32_32x32x16_bf16(ak, bq[s], S[t], 0, 0, 0);
            }

        // p = exp2(s); accumulate l in-lane; pack bf16 pairs per 8-key block:
        // w0[b] = keys(8b + 4*half + 0,1), w1[b] = keys(8b + 4*half + 2,3),
        // b = 4t + rg.  (lanes<32: lo sub-half, lanes>=32: hi sub-half)
        unsigned w0[8], w1[8];
        #pragma unroll
        for (int t = 0; t < 2; t++)
            #pragma unroll
            for (int rg = 0; rg < 4; rg++) {
                const float p0 = fast_exp2(S[t][rg * 4 + 0]);
                const float p1 = fast_exp2(S[t][rg * 4 + 1]);
                const float p2 = fast_exp2(S[t][rg * 4 + 2]);
                const float p3 = fast_exp2(S[t][rg * 4 + 3]);
                lsum += (p0 + p1) + (p2 + p3);
                w0[t * 4 + rg] = __builtin_amdgcn_perm(rnd_bf(p1), rnd_bf(p0), 0x07060302);
                w1[t * 4 + rg] = __builtin_amdgcn_perm(rnd_bf(p3), rnd_bf(p2), 0x07060302);
            }

        // build PV A-frags in-register via permlane32_swap (T12):
        // new_x[l] = l<32 ? x[l] : y[l-32]; new_y[l] = l<32 ? x[l+32] : y[l]
        short8_t ap[4];
        #pragma unroll
        for (int s = 0; s < 4; s++) {
            uintx2 q0 = __builtin_amdgcn_permlane32_swap(w0[2 * s], w0[2 * s + 1], false, false);
            uintx2 q1 = __builtin_amdgcn_permlane32_swap(w1[2 * s], w1[2 * s + 1], false, false);
            uintx4 v;
            v[0] = q0[0]; v[1] = q1[0]; v[2] = q0[1]; v[3] = q1[1];
            ap[s] = *(short8_t*)&v;
        }

        // PV: O[query][dim] += P[query][key] V^T[dim][key]
        #pragma unroll
        for (int dt = 0; dt < 2; dt++)
            #pragma unroll
            for (int s = 0; s < 4; s++) {
                const int slot = ((s * 2 + half) ^ fxr) * 8;
                short8_t bv = *(const short8_t*)&Vs[cur][(dt * 32 + c32) * 64 + slot];
                O[dt] = __builtin_amdgcn_mfma_f32_32x32x16_bf16(ap[s], bv, O[dt], 0, 0, 0);
            }
    }

    // epilogue: lanes l and l+32 hold complementary key-halves of query c32
    lsum += __shfl_xor(lsum, 32);
    if (half == 0) scr[wave][c32] = 1.0f / lsum;
    __builtin_amdgcn_s_waitcnt(0);   // drain scr write before same-wave read

    // O rows = quad queries (rg*8 + 4*half + 0..3); col dim = dt*32 + c32
    #pragma unroll
    for (int rg = 0; rg < 4; rg++) {
        const float4 inv4 = *(const float4*)&scr[wave][rg * 8 + 4 * half];
        #pragma unroll
        for (int q = 0; q < 4; q++) {
            const float invl = ((const float*)&inv4)[q];
            const size_t row = (size_t)b * SEQ + qt * ABM + wave * 32 + rg * 8 + 4 * half + q;
            #pragma unroll
            for (int dt = 0; dt < 2; dt++)
                aout[row * DIM + h * HDIM + dt * 32 + c32] = f2bf(O[dt][rg * 4 + q] * invl);
        }
    }
}

// ---------------------------------------------------------------------------
extern "C" void kernel_launch(void* const* d_in, const int* in_sizes, int n_in,
                              void* d_out, int out_size, void* d_ws, size_t ws_size,
                              hipStream_t stream) {
    const float* x      = (const float*)d_in[0];   // [8,1024,1024]
    const float* W_qkv  = (const float*)d_in[1];   // [3072,1024]
    const float* W_proj = (const float*)d_in[2];   // [1024,1024]
    const float* b_proj = (const float*)d_in[3];   // [1024]
    float* out = (float*)d_out;                    // [8,1024,1024] fp32

    const int M = BATCH * SEQ;                     // 8192

    // workspace (bf16 elements), ~92.3 MB total
    unsigned short* ws       = (unsigned short*)d_ws;
    unsigned short* x_bf     = ws;                                   // 8192*1024
    unsigned short* wqkv_bf  = x_bf + (size_t)M * DIM;               // 3072*1024
    unsigned short* wproj_bf = wqkv_bf + (size_t)3 * DIM * DIM;      // 1024*1024
    unsigned short* qk_bf    = wproj_bf + (size_t)DIM * DIM;         // 8192*2048
    unsigned short* vt_bf    = qk_bf + (size_t)M * 2048;             // 16*64*8*1024
    unsigned short* aout_bf  = vt_bf + (size_t)BATCH * HEADS * HDIM * SEQ;  // 8192*1024

    // 0) fused casts (x, W_qkv, W_proj)
    {
        const int n8 = (M * DIM + 3 * DIM * DIM + DIM * DIM) / 8;
        cvt_bf16_all<<<(n8 + 255) / 256, 256, 0, stream>>>(
            x, W_qkv, W_proj, x_bf, wqkv_bf, wproj_bf);
    }

    // 1) QKV projection (reverted to proven 128^2 kernel, r0 = 69.0 us):
    //    Q (pre-scaled) + K natural bf16 -> qk[row][2048]; V -> vt[b][h][d][n]
    gemm_nt_mfma<2><<<dim3(M / 128, 3 * DIM / 128), 256, 0, stream>>>(
        x_bf, wqkv_bf, nullptr, qk_bf, vt_bf, M, 3 * DIM, DIM);

    // 2) MFMA flash attention; grid x = (b,h) so q-tiles share an XCD
    attn_mfma<<<dim3(BATCH * HEADS, SEQ / ABM), 256, 0, stream>>>(qk_bf, vt_bf, aout_bf);

    // 3) output projection (fp32 out + bias); 128^2 tile, 512 blocks
    gemm_nt_mfma<0><<<dim3(M / 128, DIM / 128), 256, 0, stream>>>(
        aout_bf, wproj_bf, b_proj, out, nullptr, M, DIM, DIM);
}

// Round 6
// 229.297 us; speedup vs baseline: 1.0319x; 1.0319x over previous
//
#include <hip/hip_runtime.h>
#include <math.h>

#define DIM   1024
#define HEADS 16
#define HDIM  64
#define SEQ   1024
#define BATCH 8
// SCALE * log2(e): Q is pre-scaled by this in the QKV epilogue so attention
// can use exp2 directly: exp2(s*SCALE*log2e) == exp(s*SCALE).
#define QSCALE 0.1803368801111204f
#define LDH   72       // Q LDS row stride in bf16 (64 + 8 pad)
#define ABM   128      // attention query tile (32 queries per wave)

typedef __attribute__((ext_vector_type(8)))  short          short8_t;   // MFMA bf16 frag
typedef __attribute__((ext_vector_type(8)))  unsigned short ushort8_t;
typedef __attribute__((ext_vector_type(4)))  unsigned short ushort4_t;
typedef __attribute__((ext_vector_type(2)))  unsigned int   uintx2;
typedef __attribute__((ext_vector_type(4)))  unsigned int   uintx4;
typedef __attribute__((ext_vector_type(4)))  float          floatx4;
typedef __attribute__((ext_vector_type(16))) float          floatx16;

__device__ __forceinline__ unsigned short f2bf(float f) {
    unsigned u = __float_as_uint(f);
    u += 0x7fffu + ((u >> 16) & 1u);      // round-to-nearest-even
    return (unsigned short)(u >> 16);
}
__device__ __forceinline__ unsigned rnd_bf(float f) {  // RNE-rounded, bf16 in bits 31:16
    unsigned u = __float_as_uint(f);
    return u + 0x7fffu + ((u >> 16) & 1u);
}
__device__ __forceinline__ float fast_exp2(float x) {
#if __has_builtin(__builtin_amdgcn_exp2f)
    return __builtin_amdgcn_exp2f(x);
#else
    return exp2f(x);
#endif
}
__device__ __forceinline__ void glds16(const unsigned short* g, unsigned short* l) {
    __builtin_amdgcn_global_load_lds(
        (const __attribute__((address_space(1))) void*)g,
        (__attribute__((address_space(3))) void*)l, 16, 0, 0);
}

// ---------------------------------------------------------------------------
// Fused fp32 -> bf16 cast of x, W_qkv, W_proj in one launch (8 elems/thread).
// ---------------------------------------------------------------------------
__global__ __launch_bounds__(256) void cvt_bf16_all(const float* __restrict__ x,
                                                    const float* __restrict__ wqkv,
                                                    const float* __restrict__ wproj,
                                                    unsigned short* __restrict__ x_o,
                                                    unsigned short* __restrict__ wqkv_o,
                                                    unsigned short* __restrict__ wproj_o) {
    const int N8_X = BATCH * SEQ * DIM / 8;         // 1048576
    const int N8_WQ = 3 * DIM * DIM / 8;            // 393216
    const int N8_WP = DIM * DIM / 8;                // 131072
    int i = blockIdx.x * 256 + threadIdx.x;
    const float* in;
    unsigned short* out;
    if (i < N8_X)               { in = x;     out = x_o; }
    else if (i < N8_X + N8_WQ)  { i -= N8_X;  in = wqkv; out = wqkv_o; }
    else                        { i -= N8_X + N8_WQ;
                                  if (i >= N8_WP) return;
                                  in = wproj; out = wproj_o; }
    const float4* p = (const float4*)in + (size_t)i * 2;
    float4 a = p[0], b = p[1];
    ushort8_t u;
    u[0] = f2bf(a.x); u[1] = f2bf(a.y); u[2] = f2bf(a.z); u[3] = f2bf(a.w);
    u[4] = f2bf(b.x); u[5] = f2bf(b.y); u[6] = f2bf(b.z); u[7] = f2bf(b.w);
    ((ushort8_t*)out)[i] = u;
}

// ---------------------------------------------------------------------------
// C[M,N] = A[M,K] @ B[N,K]^T, bf16 in, fp32 MFMA accumulate.  128^2 tile,
// BK=64, 2-barrier glds, 8-chunk xor swizzle, 32x32x16 MFMA (2x2 accs/wave).
// Grid mapping is the r0 original: blockIdx.x = M-tile (fastest), .y = N-tile
// -> consecutive dispatch-linear blocks share ONE B-panel (256 KB, L2-hot on
// every XCD simultaneously). r5 measured that a 2-D XCD-chunked swizzle makes
// this WORSE (69.0 -> 74.4 us, FETCH 42.7 -> 47.9 MB): it raises the
// instantaneous working set (12 live B-panels/XCD) even though the per-XCD
// panel set "fits" L2. Swizzle removed.
// A/B frag: [m=lane&31][k=(lane>>5)*8+j]; C/D: col=lane&31,
// row=(reg&3)+8*(reg>>2)+4*(lane>>5)  [measured m74/m101].
// MODE 0: fp32 out + bias. MODE 2: QKV split — cols<1024 -> Q bf16 *QSCALE;
// 1024..2047 -> K bf16; >=2048 -> V TRANSPOSED to vt[b][h][d][token].
// SQ_LDS_BANK_CONFLICT ~6.29M/dispatch is the wave64 b128 floor (a 64-bf16
// row spans all 32 banks; 32-row column reads are inherently ~4-way), not a
// fixable lever.
// ---------------------------------------------------------------------------
template<int MODE>
__global__ __launch_bounds__(256) void gemm_nt_mfma(const unsigned short* __restrict__ A,
                                                    const unsigned short* __restrict__ B,
                                                    const float* __restrict__ bias,
                                                    void* __restrict__ Cout,
                                                    unsigned short* __restrict__ vt,
                                                    int M, int N, int K) {
    __shared__ __align__(16) unsigned short As[128 * 64];   // 16 KB
    __shared__ __align__(16) unsigned short Bs[128 * 64];   // 16 KB

    const int tid  = threadIdx.x;
    const int lane = tid & 63;
    const int wave = tid >> 6;
    const int wm = (wave >> 1) * 64;
    const int wn = (wave & 1) * 64;
    const size_t brow = (size_t)blockIdx.x * 128;   // M fastest (r0 mapping)
    const size_t bcol = (size_t)blockIdx.y * 128;

    const int srow   = lane >> 3;                 // 0..7
    const int schunk = (lane & 7) ^ srow;         // xor-swizzled global chunk
    const unsigned short* gA = A + (brow + wave * 8 + srow) * (size_t)K + schunk * 8;
    const unsigned short* gB = B + (bcol + wave * 8 + srow) * (size_t)K + schunk * 8;
    unsigned short* lA = &As[wave * 512 + lane * 8];
    unsigned short* lB = &Bs[wave * 512 + lane * 8];

    floatx16 acc[2][2];
    #pragma unroll
    for (int i = 0; i < 2; i++)
        #pragma unroll
        for (int j = 0; j < 2; j++)
            #pragma unroll
            for (int r = 0; r < 16; r++) acc[i][j][r] = 0.f;

    const int c32  = lane & 31;   // frag row (m for A, n for B)
    const int half = lane >> 5;   // k-half selector
    const int xr   = c32 & 7;     // row xor for swizzled reads

    for (int k0 = 0; k0 < K; k0 += 64) {
        __syncthreads();
        #pragma unroll
        for (int r = 0; r < 4; r++) {
            glds16(gA + (size_t)r * 32 * K + k0, lA + r * 2048);
            glds16(gB + (size_t)r * 32 * K + k0, lB + r * 2048);
        }
        __syncthreads();

        #pragma unroll
        for (int s = 0; s < 4; s++) {   // 4 k-steps of 16
            const int ch = ((s * 2 + half) ^ xr) * 8;   // swizzled chunk offset
            short8_t a0 = *(const short8_t*)&As[(wm + c32) * 64 + ch];
            short8_t a1 = *(const short8_t*)&As[(wm + 32 + c32) * 64 + ch];
            short8_t b0 = *(const short8_t*)&Bs[(wn + c32) * 64 + ch];
            short8_t b1 = *(const short8_t*)&Bs[(wn + 32 + c32) * 64 + ch];
            acc[0][0] = __builtin_amdgcn_mfma_f32_32x32x16_bf16(a0, b0, acc[0][0], 0, 0, 0);
            acc[0][1] = __builtin_amdgcn_mfma_f32_32x32x16_bf16(a0, b1, acc[0][1], 0, 0, 0);
            acc[1][0] = __builtin_amdgcn_mfma_f32_32x32x16_bf16(a1, b0, acc[1][0], 0, 0, 0);
            acc[1][1] = __builtin_amdgcn_mfma_f32_32x32x16_bf16(a1, b1, acc[1][1], 0, 0, 0);
        }
    }

    // C/D: col = c32, row = (r&3) + 8*(r>>2) + 4*half
    if (MODE == 0) {
        #pragma unroll
        for (int mi = 0; mi < 2; mi++)
            #pragma unroll
            for (int ni = 0; ni < 2; ni++) {
                const size_t col = bcol + wn + ni * 32 + c32;
                const float bv = bias[col];
                #pragma unroll
                for (int r = 0; r < 16; r++) {
                    const size_t row = brow + wm + mi * 32 + (r & 3) + 8 * (r >> 2) + 4 * half;
                    ((float*)Cout)[row * N + col] = acc[mi][ni][r] + bv;
                }
            }
    } else {  // MODE 2: QKV split epilogue
        if (bcol < 2048) {
            const float sc = (bcol < 1024) ? QSCALE : 1.0f;  // pre-scale Q
            unsigned short* qk = (unsigned short*)Cout;
            #pragma unroll
            for (int mi = 0; mi < 2; mi++)
                #pragma unroll
                for (int ni = 0; ni < 2; ni++) {
                    const size_t col = bcol + wn + ni * 32 + c32;
                    #pragma unroll
                    for (int r = 0; r < 16; r++) {
                        const size_t row = brow + wm + mi * 32 + (r & 3) + 8 * (r >> 2) + 4 * half;
                        qk[row * 2048 + col] = f2bf(acc[mi][ni][r] * sc);
                    }
                }
        } else {
            #pragma unroll
            for (int mi = 0; mi < 2; mi++)
                #pragma unroll
                for (int ni = 0; ni < 2; ni++) {
                    const int dall = (int)(bcol + wn + ni * 32 + c32) - 2048;
                    const int h = dall >> 6, d = dall & 63;
                    #pragma unroll
                    for (int rg = 0; rg < 4; rg++) {   // reg-quad = 4 consecutive rows
                        const size_t row0 = brow + wm + mi * 32 + rg * 8 + 4 * half;
                        const size_t bb = row0 >> 10;
                        const int n0 = (int)(row0 & 1023);
                        ushort4_t o;
                        #pragma unroll
                        for (int q = 0; q < 4; q++) o[q] = f2bf(acc[mi][ni][rg * 4 + q]);
                        *(ushort4_t*)&vt[(((size_t)bb * HEADS + h) * HDIM + d) * SEQ + n0] = o;
                    }
                }
        }
    }
}

// ---------------------------------------------------------------------------
// MFMA flash attention, S^T formulation with 32x32x16 MFMA. ABM=128, 4 waves;
// wave w owns queries w*32 + (lane&31). Per 64-key tile (dbuf LDS, one
// barrier, register prefetch after the barrier):
//   S^T = K Q^T via 8 mfma_32x32x16 (2 key-row-tiles x 4 k-steps).
//   C-layout: col = query (lane&31) -> each lane owns ONE query; rows = keys
//   (r&3)+8(r>>2)+4*half (+t*32): lanes l and l^32 hold complementary 4-key
//   sub-halves of every 8-key block -> lsum reduction is one shfl_xor(32).
//   p = exp2(s) (Q pre-scaled; no max tracking).
//   P -> PV A-frags ENTIRELY IN REGISTERS (T12, verified r5): pack quads to
//   bf16 words w0[b],w1[b] (b = 4t+rg = 8-key block; lanes<32 hold lo-pairs,
//   lanes>=32 hi-pairs), then ap32 words via v_permlane32_swap:
//     (ap32[0], ap32[2]) = swap(w0[2s], w0[2s+1])
//     (ap32[1], ap32[3]) = swap(w1[2s], w1[2s+1])
//   -> half0 lanes get block 2s, half1 lanes block 2s+1, exactly the
//   A-frag's k=(lane>>5)*8+j layout. Replaces the former per-tile LDS P
//   round-trip (8 ds_write_b64 + 4 ds_read_b128 + in-order DS latency)
//   with 8 VALU-rate permlanes.
//   PV: O[query][dim] += P V^T, B = V^T[dim][key] frags from LDS.
// Grid = (b*HEADS+h, qt): XCD-local K/V.
// ---------------------------------------------------------------------------
__global__ __launch_bounds__(256) void attn_mfma(const unsigned short* __restrict__ qk,
                                                 const unsigned short* __restrict__ vt,
                                                 unsigned short* __restrict__ aout) {
    const int bh = blockIdx.x;           // b*HEADS + h
    const int qt = blockIdx.y;           // 0..7
    const int h  = bh & 15;
    const int b  = bh >> 4;
    const int tid  = threadIdx.x;
    const int lane = tid & 63;
    const int wave = tid >> 6;
    const int c32  = lane & 31;   // query index within wave's 32
    const int half = lane >> 5;   // k-half / key-row-half selector

    __shared__ __align__(16) unsigned short Qs[ABM * LDH];      // Q staging
    __shared__ __align__(16) unsigned short Ks[2][64 * 64];     // swizzled
    __shared__ __align__(16) unsigned short Vs[2][64 * 64];     // V^T, swizzled
    __shared__ float scr[4][32];

    const int sr = tid >> 2;   // K/V staging row 0..63
    const int sq = tid & 3;    // two 16B chunks: 2sq, 2sq+1 (pre-swizzle)
    const int sx = sr & 7;     // staging row xor
    const unsigned short* ksrc0 =
        qk + ((size_t)(b * SEQ + sr)) * 2048 + DIM + h * HDIM + sq * 16;
    const unsigned short* vsrc0 =
        vt + (((size_t)(b * HEADS + h)) * HDIM + sr) * SEQ + sq * 16;
    // swizzled LDS staging offsets (bf16 units): row*64 + (chunk^xr)*8
    const int kvo0 = sr * 64 + (((sq * 2)     ^ sx) * 8);
    const int kvo1 = sr * 64 + (((sq * 2 + 1) ^ sx) * 8);

    // prefetch K/V tile 0 into registers
    ushort8_t ck0 = *(const ushort8_t*)ksrc0;
    ushort8_t ck1 = *(const ushort8_t*)(ksrc0 + 8);
    ushort8_t cv0 = *(const ushort8_t*)vsrc0;
    ushort8_t cv1 = *(const ushort8_t*)(vsrc0 + 8);

    // stage Q tile: 128 rows x 64 cols; thread -> row tid>>1, 32-col half
    {
        const int r  = tid >> 1;
        const int c0 = (tid & 1) * 32;
        const unsigned short* src =
            qk + ((size_t)(b * SEQ + qt * ABM + r)) * 2048 + h * HDIM + c0;
        unsigned short* dst = &Qs[r * LDH + c0];
        *(ushort8_t*)(dst)      = *(const ushort8_t*)(src);
        *(ushort8_t*)(dst + 8)  = *(const ushort8_t*)(src + 8);
        *(ushort8_t*)(dst + 16) = *(const ushort8_t*)(src + 16);
        *(ushort8_t*)(dst + 24) = *(const ushort8_t*)(src + 24);
    }
    __syncthreads();

    // Q B-fragments (4 k-steps of 16 dims), register-resident for the kernel
    short8_t bq[4];
    #pragma unroll
    for (int s = 0; s < 4; s++)
        bq[s] = *(const short8_t*)&Qs[(wave * 32 + c32) * LDH + s * 16 + half * 8];

    floatx16 O[2];   // O[dt]: rows = quad queries, col dim = dt*32 + c32
    #pragma unroll
    for (int dt = 0; dt < 2; dt++)
        #pragma unroll
        for (int r = 0; r < 16; r++) O[dt][r] = 0.f;
    float lsum = 0.f;

    const int fxr = c32 & 7;   // frag-read row xor (rows step by 32)

    for (int kt = 0; kt < SEQ / 64; kt++) {
        const int cur = kt & 1;
        // write prefetched K/V into buf[cur] (vmcnt wait lands here, a full
        // MFMA phase after the loads were issued)
        *(ushort8_t*)&Ks[cur][kvo0] = ck0;
        *(ushort8_t*)&Ks[cur][kvo1] = ck1;
        *(ushort8_t*)&Vs[cur][kvo0] = cv0;
        *(ushort8_t*)&Vs[cur][kvo1] = cv1;
        __syncthreads();   // ONE barrier per tile
        // issue next tile's global loads AFTER the barrier
        if (kt + 1 < SEQ / 64) {
            const unsigned short* ks = ksrc0 + (size_t)(kt + 1) * 64 * 2048;
            const unsigned short* vs = vsrc0 + (kt + 1) * 64;
            ck0 = *(const ushort8_t*)ks;
            ck1 = *(const ushort8_t*)(ks + 8);
            cv0 = *(const ushort8_t*)vs;
            cv1 = *(const ushort8_t*)(vs + 8);
        }

        // S^T = K Q^T : 2 key-row-tiles x 4 k-steps of 32x32x16
        floatx16 S[2];
        #pragma unroll
        for (int t = 0; t < 2; t++)
            #pragma unroll
            for (int r = 0; r < 16; r++) S[t][r] = 0.f;
        #pragma unroll
        for (int t = 0; t < 2; t++)
            #pragma unroll
            for (int s = 0; s < 4; s++) {
                const int slot = ((s * 2 + half) ^ fxr) * 8;
                short8_t ak = *(const short8_t*)&Ks[cur][(t * 32 + c32) * 64 + slot];
                S[t] = __builtin_amdgcn_mfma_f32_32x32x16_bf16(ak, bq[s], S[t], 0, 0, 0);
            }

        // p = exp2(s); accumulate l in-lane; pack bf16 pairs per 8-key block:
        // w0[b] = keys(8b + 4*half + 0,1), w1[b] = keys(8b + 4*half + 2,3),
        // b = 4t + rg.  (lanes<32: lo sub-half, lanes>=32: hi sub-half)
        unsigned w0[8], w1[8];
        #pragma unroll
        for (int t = 0; t < 2; t++)
            #pragma unroll
            for (int rg = 0; rg < 4; rg++) {
                const float p0 = fast_exp2(S[t][rg * 4 + 0]);
                const float p1 = fast_exp2(S[t][rg * 4 + 1]);
                const float p2 = fast_exp2(S[t][rg * 4 + 2]);
                const float p3 = fast_exp2(S[t][rg * 4 + 3]);
                lsum += (p0 + p1) + (p2 + p3);
                w0[t * 4 + rg] = __builtin_amdgcn_perm(rnd_bf(p1), rnd_bf(p0), 0x07060302);
                w1[t * 4 + rg] = __builtin_amdgcn_perm(rnd_bf(p3), rnd_bf(p2), 0x07060302);
            }

        // build PV A-frags in-register via permlane32_swap (T12):
        // new_x[l] = l<32 ? x[l] : y[l-32]; new_y[l] = l<32 ? x[l+32] : y[l]
        short8_t ap[4];
        #pragma unroll
        for (int s = 0; s < 4; s++) {
            uintx2 q0 = __builtin_amdgcn_permlane32_swap(w0[2 * s], w0[2 * s + 1], false, false);
            uintx2 q1 = __builtin_amdgcn_permlane32_swap(w1[2 * s], w1[2 * s + 1], false, false);
            uintx4 v;
            v[0] = q0[0]; v[1] = q1[0]; v[2] = q0[1]; v[3] = q1[1];
            ap[s] = *(short8_t*)&v;
        }

        // PV: O[query][dim] += P[query][key] V^T[dim][key]
        #pragma unroll
        for (int dt = 0; dt < 2; dt++)
            #pragma unroll
            for (int s = 0; s < 4; s++) {
                const int slot = ((s * 2 + half) ^ fxr) * 8;
                short8_t bv = *(const short8_t*)&Vs[cur][(dt * 32 + c32) * 64 + slot];
                O[dt] = __builtin_amdgcn_mfma_f32_32x32x16_bf16(ap[s], bv, O[dt], 0, 0, 0);
            }
    }

    // epilogue: lanes l and l+32 hold complementary key-halves of query c32
    lsum += __shfl_xor(lsum, 32);
    if (half == 0) scr[wave][c32] = 1.0f / lsum;
    __builtin_amdgcn_s_waitcnt(0);   // drain scr write before same-wave read

    // O rows = quad queries (rg*8 + 4*half + 0..3); col dim = dt*32 + c32
    #pragma unroll
    for (int rg = 0; rg < 4; rg++) {
        const float4 inv4 = *(const float4*)&scr[wave][rg * 8 + 4 * half];
        #pragma unroll
        for (int q = 0; q < 4; q++) {
            const float invl = ((const float*)&inv4)[q];
            const size_t row = (size_t)b * SEQ + qt * ABM + wave * 32 + rg * 8 + 4 * half + q;
            #pragma unroll
            for (int dt = 0; dt < 2; dt++)
                aout[row * DIM + h * HDIM + dt * 32 + c32] = f2bf(O[dt][rg * 4 + q] * invl);
        }
    }
}

// ---------------------------------------------------------------------------
extern "C" void kernel_launch(void* const* d_in, const int* in_sizes, int n_in,
                              void* d_out, int out_size, void* d_ws, size_t ws_size,
                              hipStream_t stream) {
    const float* x      = (const float*)d_in[0];   // [8,1024,1024]
    const float* W_qkv  = (const float*)d_in[1];   // [3072,1024]
    const float* W_proj = (const float*)d_in[2];   // [1024,1024]
    const float* b_proj = (const float*)d_in[3];   // [1024]
    float* out = (float*)d_out;                    // [8,1024,1024] fp32

    const int M = BATCH * SEQ;                     // 8192

    // workspace (bf16 elements), ~92.3 MB total
    unsigned short* ws       = (unsigned short*)d_ws;
    unsigned short* x_bf     = ws;                                   // 8192*1024
    unsigned short* wqkv_bf  = x_bf + (size_t)M * DIM;               // 3072*1024
    unsigned short* wproj_bf = wqkv_bf + (size_t)3 * DIM * DIM;      // 1024*1024
    unsigned short* qk_bf    = wproj_bf + (size_t)DIM * DIM;         // 8192*2048
    unsigned short* vt_bf    = qk_bf + (size_t)M * 2048;             // 16*64*8*1024
    unsigned short* aout_bf  = vt_bf + (size_t)BATCH * HEADS * HDIM * SEQ;  // 8192*1024

    // 0) fused casts (x, W_qkv, W_proj)
    {
        const int n8 = (M * DIM + 3 * DIM * DIM + DIM * DIM) / 8;
        cvt_bf16_all<<<(n8 + 255) / 256, 256, 0, stream>>>(
            x, W_qkv, W_proj, x_bf, wqkv_bf, wproj_bf);
    }

    // 1) QKV projection (r0 kernel + r0 grid mapping, measured 69.0 us):
    //    Q (pre-scaled) + K natural bf16 -> qk[row][2048]; V -> vt[b][h][d][n]
    gemm_nt_mfma<2><<<dim3(M / 128, 3 * DIM / 128), 256, 0, stream>>>(
        x_bf, wqkv_bf, nullptr, qk_bf, vt_bf, M, 3 * DIM, DIM);

    // 2) MFMA flash attention; grid x = (b,h) so q-tiles share an XCD
    attn_mfma<<<dim3(BATCH * HEADS, SEQ / ABM), 256, 0, stream>>>(qk_bf, vt_bf, aout_bf);

    // 3) output projection (fp32 out + bias); 128^2 tile, 512 blocks
    gemm_nt_mfma<0><<<dim3(M / 128, DIM / 128), 256, 0, stream>>>(
        aout_bf, wproj_bf, b_proj, out, nullptr, M, DIM, DIM);
}

// Round 7
// 223.640 us; speedup vs baseline: 1.0580x; 1.0253x over previous
//
#include <hip/hip_runtime.h>
#include <math.h>

#define DIM   1024
#define HEADS 16
#define HDIM  64
#define SEQ   1024
#define BATCH 8
// SCALE * log2(e): Q is pre-scaled by this in the QKV epilogue so attention
// can use exp2 directly: exp2(s*SCALE*log2e) == exp(s*SCALE).
#define QSCALE 0.1803368801111204f
#define LDQ   72       // transient Q staging row stride in bf16 (64 + 8 pad)
#define ABM   128      // attention query tile (32 queries per wave)

typedef __attribute__((ext_vector_type(8)))  short          short8_t;   // MFMA bf16 frag
typedef __attribute__((ext_vector_type(8)))  unsigned short ushort8_t;
typedef __attribute__((ext_vector_type(4)))  unsigned short ushort4_t;
typedef __attribute__((ext_vector_type(2)))  unsigned int   uintx2;
typedef __attribute__((ext_vector_type(4)))  unsigned int   uintx4;
typedef __attribute__((ext_vector_type(4)))  float          floatx4;
typedef __attribute__((ext_vector_type(16))) float          floatx16;

__device__ __forceinline__ unsigned short f2bf(float f) {
    unsigned u = __float_as_uint(f);
    u += 0x7fffu + ((u >> 16) & 1u);      // round-to-nearest-even
    return (unsigned short)(u >> 16);
}
__device__ __forceinline__ unsigned rnd_bf(float f) {  // RNE-rounded, bf16 in bits 31:16
    unsigned u = __float_as_uint(f);
    return u + 0x7fffu + ((u >> 16) & 1u);
}
__device__ __forceinline__ float fast_exp2(float x) {
#if __has_builtin(__builtin_amdgcn_exp2f)
    return __builtin_amdgcn_exp2f(x);
#else
    return exp2f(x);
#endif
}
__device__ __forceinline__ void glds16(const unsigned short* g, unsigned short* l) {
    __builtin_amdgcn_global_load_lds(
        (const __attribute__((address_space(1))) void*)g,
        (__attribute__((address_space(3))) void*)l, 16, 0, 0);
}

// ---------------------------------------------------------------------------
// Fused fp32 -> bf16 cast of x, W_qkv, W_proj in one launch (8 elems/thread).
// ---------------------------------------------------------------------------
__global__ __launch_bounds__(256) void cvt_bf16_all(const float* __restrict__ x,
                                                    const float* __restrict__ wqkv,
                                                    const float* __restrict__ wproj,
                                                    unsigned short* __restrict__ x_o,
                                                    unsigned short* __restrict__ wqkv_o,
                                                    unsigned short* __restrict__ wproj_o) {
    const int N8_X = BATCH * SEQ * DIM / 8;         // 1048576
    const int N8_WQ = 3 * DIM * DIM / 8;            // 393216
    const int N8_WP = DIM * DIM / 8;                // 131072
    int i = blockIdx.x * 256 + threadIdx.x;
    const float* in;
    unsigned short* out;
    if (i < N8_X)               { in = x;     out = x_o; }
    else if (i < N8_X + N8_WQ)  { i -= N8_X;  in = wqkv; out = wqkv_o; }
    else                        { i -= N8_X + N8_WQ;
                                  if (i >= N8_WP) return;
                                  in = wproj; out = wproj_o; }
    const float4* p = (const float4*)in + (size_t)i * 2;
    float4 a = p[0], b = p[1];
    ushort8_t u;
    u[0] = f2bf(a.x); u[1] = f2bf(a.y); u[2] = f2bf(a.z); u[3] = f2bf(a.w);
    u[4] = f2bf(b.x); u[5] = f2bf(b.y); u[6] = f2bf(b.z); u[7] = f2bf(b.w);
    ((ushort8_t*)out)[i] = u;
}

// ---------------------------------------------------------------------------
// C[M,N] = A[M,K] @ B[N,K]^T, bf16 in, fp32 MFMA accumulate.  128^2 tile,
// BK=64, 2-barrier glds, 8-chunk xor swizzle, 32x32x16 MFMA (2x2 accs/wave).
// Grid mapping is the r0 original: blockIdx.x = M-tile (fastest), .y = N-tile
// -> consecutive dispatch-linear blocks share ONE B-panel (256 KB, L2-hot on
// every XCD simultaneously). r5 measured that a 2-D XCD-chunked swizzle makes
// this WORSE (69.0 -> 74.4 us, FETCH 42.7 -> 47.9 MB). Swizzle removed.
// A/B frag: [m=lane&31][k=(lane>>5)*8+j]; C/D: col=lane&31,
// row=(reg&3)+8*(reg>>2)+4*(lane>>5)  [measured m74/m101].
// MODE 0: fp32 out + bias. MODE 2: QKV split — cols<1024 -> Q bf16 *QSCALE;
// 1024..2047 -> K bf16; >=2048 -> V TRANSPOSED to vt[b][h][d][token].
// SQ_LDS_BANK_CONFLICT ~6.29M/dispatch is the wave64 b128 floor, not a
// fixable lever.
// ---------------------------------------------------------------------------
template<int MODE>
__global__ __launch_bounds__(256) void gemm_nt_mfma(const unsigned short* __restrict__ A,
                                                    const unsigned short* __restrict__ B,
                                                    const float* __restrict__ bias,
                                                    void* __restrict__ Cout,
                                                    unsigned short* __restrict__ vt,
                                                    int M, int N, int K) {
    __shared__ __align__(16) unsigned short As[128 * 64];   // 16 KB
    __shared__ __align__(16) unsigned short Bs[128 * 64];   // 16 KB

    const int tid  = threadIdx.x;
    const int lane = tid & 63;
    const int wave = tid >> 6;
    const int wm = (wave >> 1) * 64;
    const int wn = (wave & 1) * 64;
    const size_t brow = (size_t)blockIdx.x * 128;   // M fastest (r0 mapping)
    const size_t bcol = (size_t)blockIdx.y * 128;

    const int srow   = lane >> 3;                 // 0..7
    const int schunk = (lane & 7) ^ srow;         // xor-swizzled global chunk
    const unsigned short* gA = A + (brow + wave * 8 + srow) * (size_t)K + schunk * 8;
    const unsigned short* gB = B + (bcol + wave * 8 + srow) * (size_t)K + schunk * 8;
    unsigned short* lA = &As[wave * 512 + lane * 8];
    unsigned short* lB = &Bs[wave * 512 + lane * 8];

    floatx16 acc[2][2];
    #pragma unroll
    for (int i = 0; i < 2; i++)
        #pragma unroll
        for (int j = 0; j < 2; j++)
            #pragma unroll
            for (int r = 0; r < 16; r++) acc[i][j][r] = 0.f;

    const int c32  = lane & 31;   // frag row (m for A, n for B)
    const int half = lane >> 5;   // k-half selector
    const int xr   = c32 & 7;     // row xor for swizzled reads

    for (int k0 = 0; k0 < K; k0 += 64) {
        __syncthreads();
        #pragma unroll
        for (int r = 0; r < 4; r++) {
            glds16(gA + (size_t)r * 32 * K + k0, lA + r * 2048);
            glds16(gB + (size_t)r * 32 * K + k0, lB + r * 2048);
        }
        __syncthreads();

        #pragma unroll
        for (int s = 0; s < 4; s++) {   // 4 k-steps of 16
            const int ch = ((s * 2 + half) ^ xr) * 8;   // swizzled chunk offset
            short8_t a0 = *(const short8_t*)&As[(wm + c32) * 64 + ch];
            short8_t a1 = *(const short8_t*)&As[(wm + 32 + c32) * 64 + ch];
            short8_t b0 = *(const short8_t*)&Bs[(wn + c32) * 64 + ch];
            short8_t b1 = *(const short8_t*)&Bs[(wn + 32 + c32) * 64 + ch];
            acc[0][0] = __builtin_amdgcn_mfma_f32_32x32x16_bf16(a0, b0, acc[0][0], 0, 0, 0);
            acc[0][1] = __builtin_amdgcn_mfma_f32_32x32x16_bf16(a0, b1, acc[0][1], 0, 0, 0);
            acc[1][0] = __builtin_amdgcn_mfma_f32_32x32x16_bf16(a1, b0, acc[1][0], 0, 0, 0);
            acc[1][1] = __builtin_amdgcn_mfma_f32_32x32x16_bf16(a1, b1, acc[1][1], 0, 0, 0);
        }
    }

    // C/D: col = c32, row = (r&3) + 8*(r>>2) + 4*half
    if (MODE == 0) {
        #pragma unroll
        for (int mi = 0; mi < 2; mi++)
            #pragma unroll
            for (int ni = 0; ni < 2; ni++) {
                const size_t col = bcol + wn + ni * 32 + c32;
                const float bv = bias[col];
                #pragma unroll
                for (int r = 0; r < 16; r++) {
                    const size_t row = brow + wm + mi * 32 + (r & 3) + 8 * (r >> 2) + 4 * half;
                    ((float*)Cout)[row * N + col] = acc[mi][ni][r] + bv;
                }
            }
    } else {  // MODE 2: QKV split epilogue
        if (bcol < 2048) {
            const float sc = (bcol < 1024) ? QSCALE : 1.0f;  // pre-scale Q
            unsigned short* qk = (unsigned short*)Cout;
            #pragma unroll
            for (int mi = 0; mi < 2; mi++)
                #pragma unroll
                for (int ni = 0; ni < 2; ni++) {
                    const size_t col = bcol + wn + ni * 32 + c32;
                    #pragma unroll
                    for (int r = 0; r < 16; r++) {
                        const size_t row = brow + wm + mi * 32 + (r & 3) + 8 * (r >> 2) + 4 * half;
                        qk[row * 2048 + col] = f2bf(acc[mi][ni][r] * sc);
                    }
                }
        } else {
            #pragma unroll
            for (int mi = 0; mi < 2; mi++)
                #pragma unroll
                for (int ni = 0; ni < 2; ni++) {
                    const int dall = (int)(bcol + wn + ni * 32 + c32) - 2048;
                    const int h = dall >> 6, d = dall & 63;
                    #pragma unroll
                    for (int rg = 0; rg < 4; rg++) {   // reg-quad = 4 consecutive rows
                        const size_t row0 = brow + wm + mi * 32 + rg * 8 + 4 * half;
                        const size_t bb = row0 >> 10;
                        const int n0 = (int)(row0 & 1023);
                        ushort4_t o;
                        #pragma unroll
                        for (int q = 0; q < 4; q++) o[q] = f2bf(acc[mi][ni][rg * 4 + q]);
                        *(ushort4_t*)&vt[(((size_t)bb * HEADS + h) * HDIM + d) * SEQ + n0] = o;
                    }
                }
        }
    }
}

// ---------------------------------------------------------------------------
// MFMA flash attention, S^T formulation with 32x32x16 MFMA. ABM=128, 4 waves;
// wave w owns queries w*32 + (lane&31).
// LDS: ONE 32 KB pool. Layout: Ks[buf] = smem + buf*4096, Vs[buf] = smem +
// 8192 + buf*4096 (bf16 units). Q staging (128 x LDQ = 18 KB) is TRANSIENT
// and aliases the pool: it is fully consumed into registers (bq) before the
// K/V tile-0 writes (fenced by __syncthreads). Since the permlane P path
// (r5) removed the per-tile P round-trip, Qs dead space was the only thing
// keeping LDS at 51.7 KB / 3 blocks-per-CU; now 32.5 KB -> 4 blocks/CU and
// the 1024-block grid is exactly one full-machine round.
// __launch_bounds__(256,4) pins VGPR <= 128 so regalloc doesn't cap
// occupancy below the LDS limit.
// Per 64-key tile (dbuf, one barrier, register prefetch after the barrier):
//   S^T = K Q^T via 8 mfma; C-layout: col = query (lane&31), rows = keys
//   (r&3)+8(r>>2)+4*half (+t*32); lanes l, l^32 complementary -> lsum is one
//   shfl_xor(32). p = exp2(s), packed to bf16 words w0/w1, redistributed to
//   PV A-frags via v_permlane32_swap (verified r5):
//     (ap32[0], ap32[2]) = swap(w0[2s], w0[2s+1])
//     (ap32[1], ap32[3]) = swap(w1[2s], w1[2s+1])
//   PV: O += P V^T, B-frags from Vs.
// Grid = (b*HEADS+h, qt): XCD-local K/V.
// ---------------------------------------------------------------------------
__global__ __launch_bounds__(256, 4) void attn_mfma(const unsigned short* __restrict__ qk,
                                                    const unsigned short* __restrict__ vt,
                                                    unsigned short* __restrict__ aout) {
    const int bh = blockIdx.x;           // b*HEADS + h
    const int qt = blockIdx.y;           // 0..7
    const int h  = bh & 15;
    const int b  = bh >> 4;
    const int tid  = threadIdx.x;
    const int lane = tid & 63;
    const int wave = tid >> 6;
    const int c32  = lane & 31;   // query index within wave's 32
    const int half = lane >> 5;   // k-half / key-row-half selector

    __shared__ __align__(16) unsigned short smem[16384];   // 32 KB pool
    __shared__ float scr[4][32];
    unsigned short* Ks0 = smem;           // + cur*4096
    unsigned short* Vs0 = smem + 8192;    // + cur*4096

    const int sr = tid >> 2;   // K/V staging row 0..63
    const int sq = tid & 3;    // two 16B chunks: 2sq, 2sq+1 (pre-swizzle)
    const int sx = sr & 7;     // staging row xor
    const unsigned short* ksrc0 =
        qk + ((size_t)(b * SEQ + sr)) * 2048 + DIM + h * HDIM + sq * 16;
    const unsigned short* vsrc0 =
        vt + (((size_t)(b * HEADS + h)) * HDIM + sr) * SEQ + sq * 16;
    // swizzled LDS staging offsets (bf16 units): row*64 + (chunk^xr)*8
    const int kvo0 = sr * 64 + (((sq * 2)     ^ sx) * 8);
    const int kvo1 = sr * 64 + (((sq * 2 + 1) ^ sx) * 8);

    // prefetch K/V tile 0 into registers
    ushort8_t ck0 = *(const ushort8_t*)ksrc0;
    ushort8_t ck1 = *(const ushort8_t*)(ksrc0 + 8);
    ushort8_t cv0 = *(const ushort8_t*)vsrc0;
    ushort8_t cv1 = *(const ushort8_t*)(vsrc0 + 8);

    // stage Q tile into the TRANSIENT aliased region: 128 rows x 64 cols,
    // row stride LDQ; thread -> row tid>>1, 32-col half
    {
        const int r  = tid >> 1;
        const int c0 = (tid & 1) * 32;
        const unsigned short* src =
            qk + ((size_t)(b * SEQ + qt * ABM + r)) * 2048 + h * HDIM + c0;
        unsigned short* dst = &smem[r * LDQ + c0];
        *(ushort8_t*)(dst)      = *(const ushort8_t*)(src);
        *(ushort8_t*)(dst + 8)  = *(const ushort8_t*)(src + 8);
        *(ushort8_t*)(dst + 16) = *(const ushort8_t*)(src + 16);
        *(ushort8_t*)(dst + 24) = *(const ushort8_t*)(src + 24);
    }
    __syncthreads();

    // Q B-fragments (4 k-steps of 16 dims), register-resident for the kernel
    short8_t bq[4];
    #pragma unroll
    for (int s = 0; s < 4; s++)
        bq[s] = *(const short8_t*)&smem[(wave * 32 + c32) * LDQ + s * 16 + half * 8];
    __syncthreads();   // all bq reads done before tile-0 staging overwrites

    floatx16 O[2];   // O[dt]: rows = quad queries, col dim = dt*32 + c32
    #pragma unroll
    for (int dt = 0; dt < 2; dt++)
        #pragma unroll
        for (int r = 0; r < 16; r++) O[dt][r] = 0.f;
    float lsum = 0.f;

    const int fxr = c32 & 7;   // frag-read row xor (rows step by 32)

    for (int kt = 0; kt < SEQ / 64; kt++) {
        const int cb = (kt & 1) * 4096;   // current buffer offset
        // write prefetched K/V into buf[cur] (vmcnt wait lands here, a full
        // MFMA phase after the loads were issued)
        *(ushort8_t*)&Ks0[cb + kvo0] = ck0;
        *(ushort8_t*)&Ks0[cb + kvo1] = ck1;
        *(ushort8_t*)&Vs0[cb + kvo0] = cv0;
        *(ushort8_t*)&Vs0[cb + kvo1] = cv1;
        __syncthreads();   // ONE barrier per tile
        // issue next tile's global loads AFTER the barrier
        if (kt + 1 < SEQ / 64) {
            const unsigned short* ks = ksrc0 + (size_t)(kt + 1) * 64 * 2048;
            const unsigned short* vs = vsrc0 + (kt + 1) * 64;
            ck0 = *(const ushort8_t*)ks;
            ck1 = *(const ushort8_t*)(ks + 8);
            cv0 = *(const ushort8_t*)vs;
            cv1 = *(const ushort8_t*)(vs + 8);
        }

        // S^T = K Q^T : 2 key-row-tiles x 4 k-steps of 32x32x16
        floatx16 S[2];
        #pragma unroll
        for (int t = 0; t < 2; t++)
            #pragma unroll
            for (int r = 0; r < 16; r++) S[t][r] = 0.f;
        #pragma unroll
        for (int t = 0; t < 2; t++)
            #pragma unroll
            for (int s = 0; s < 4; s++) {
                const int slot = ((s * 2 + half) ^ fxr) * 8;
                short8_t ak = *(const short8_t*)&Ks0[cb + (t * 32 + c32) * 64 + slot];
                S[t] = __builtin_amdgcn_mfma_f32_32x32x16_bf16(ak, bq[s], S[t], 0, 0, 0);
            }

        // p = exp2(s); accumulate l in-lane; pack bf16 pairs per 8-key block:
        // w0[b] = keys(8b + 4*half + 0,1), w1[b] = keys(8b + 4*half + 2,3),
        // b = 4t + rg.  (lanes<32: lo sub-half, lanes>=32: hi sub-half)
        unsigned w0[8], w1[8];
        #pragma unroll
        for (int t = 0; t < 2; t++)
            #pragma unroll
            for (int rg = 0; rg < 4; rg++) {
                const float p0 = fast_exp2(S[t][rg * 4 + 0]);
                const float p1 = fast_exp2(S[t][rg * 4 + 1]);
                const float p2 = fast_exp2(S[t][rg * 4 + 2]);
                const float p3 = fast_exp2(S[t][rg * 4 + 3]);
                lsum += (p0 + p1) + (p2 + p3);
                w0[t * 4 + rg] = __builtin_amdgcn_perm(rnd_bf(p1), rnd_bf(p0), 0x07060302);
                w1[t * 4 + rg] = __builtin_amdgcn_perm(rnd_bf(p3), rnd_bf(p2), 0x07060302);
            }

        // build PV A-frags in-register via permlane32_swap (T12):
        // new_x[l] = l<32 ? x[l] : y[l-32]; new_y[l] = l<32 ? x[l+32] : y[l]
        short8_t ap[4];
        #pragma unroll
        for (int s = 0; s < 4; s++) {
            uintx2 q0 = __builtin_amdgcn_permlane32_swap(w0[2 * s], w0[2 * s + 1], false, false);
            uintx2 q1 = __builtin_amdgcn_permlane32_swap(w1[2 * s], w1[2 * s + 1], false, false);
            uintx4 v;
            v[0] = q0[0]; v[1] = q1[0]; v[2] = q0[1]; v[3] = q1[1];
            ap[s] = *(short8_t*)&v;
        }

        // PV: O[query][dim] += P[query][key] V^T[dim][key]
        #pragma unroll
        for (int dt = 0; dt < 2; dt++)
            #pragma unroll
            for (int s = 0; s < 4; s++) {
                const int slot = ((s * 2 + half) ^ fxr) * 8;
                short8_t bv = *(const short8_t*)&Vs0[cb + (dt * 32 + c32) * 64 + slot];
                O[dt] = __builtin_amdgcn_mfma_f32_32x32x16_bf16(ap[s], bv, O[dt], 0, 0, 0);
            }
    }

    // epilogue: lanes l and l+32 hold complementary key-halves of query c32
    lsum += __shfl_xor(lsum, 32);
    if (half == 0) scr[wave][c32] = 1.0f / lsum;
    __builtin_amdgcn_s_waitcnt(0);   // drain scr write before same-wave read

    // O rows = quad queries (rg*8 + 4*half + 0..3); col dim = dt*32 + c32
    #pragma unroll
    for (int rg = 0; rg < 4; rg++) {
        const float4 inv4 = *(const float4*)&scr[wave][rg * 8 + 4 * half];
        #pragma unroll
        for (int q = 0; q < 4; q++) {
            const float invl = ((const float*)&inv4)[q];
            const size_t row = (size_t)b * SEQ + qt * ABM + wave * 32 + rg * 8 + 4 * half + q;
            #pragma unroll
            for (int dt = 0; dt < 2; dt++)
                aout[row * DIM + h * HDIM + dt * 32 + c32] = f2bf(O[dt][rg * 4 + q] * invl);
        }
    }
}

// ---------------------------------------------------------------------------
extern "C" void kernel_launch(void* const* d_in, const int* in_sizes, int n_in,
                              void* d_out, int out_size, void* d_ws, size_t ws_size,
                              hipStream_t stream) {
    const float* x      = (const float*)d_in[0];   // [8,1024,1024]
    const float* W_qkv  = (const float*)d_in[1];   // [3072,1024]
    const float* W_proj = (const float*)d_in[2];   // [1024,1024]
    const float* b_proj = (const float*)d_in[3];   // [1024]
    float* out = (float*)d_out;                    // [8,1024,1024] fp32

    const int M = BATCH * SEQ;                     // 8192

    // workspace (bf16 elements), ~92.3 MB total
    unsigned short* ws       = (unsigned short*)d_ws;
    unsigned short* x_bf     = ws;                                   // 8192*1024
    unsigned short* wqkv_bf  = x_bf + (size_t)M * DIM;               // 3072*1024
    unsigned short* wproj_bf = wqkv_bf + (size_t)3 * DIM * DIM;      // 1024*1024
    unsigned short* qk_bf    = wproj_bf + (size_t)DIM * DIM;         // 8192*2048
    unsigned short* vt_bf    = qk_bf + (size_t)M * 2048;             // 16*64*8*1024
    unsigned short* aout_bf  = vt_bf + (size_t)BATCH * HEADS * HDIM * SEQ;  // 8192*1024

    // 0) fused casts (x, W_qkv, W_proj)
    {
        const int n8 = (M * DIM + 3 * DIM * DIM + DIM * DIM) / 8;
        cvt_bf16_all<<<(n8 + 255) / 256, 256, 0, stream>>>(
            x, W_qkv, W_proj, x_bf, wqkv_bf, wproj_bf);
    }

    // 1) QKV projection (r0 kernel + r0 grid mapping, measured 69.0 us):
    //    Q (pre-scaled) + K natural bf16 -> qk[row][2048]; V -> vt[b][h][d][n]
    gemm_nt_mfma<2><<<dim3(M / 128, 3 * DIM / 128), 256, 0, stream>>>(
        x_bf, wqkv_bf, nullptr, qk_bf, vt_bf, M, 3 * DIM, DIM);

    // 2) MFMA flash attention; grid x = (b,h) so q-tiles share an XCD.
    //    1024 blocks at 4 blocks/CU = exactly one full-machine round.
    attn_mfma<<<dim3(BATCH * HEADS, SEQ / ABM), 256, 0, stream>>>(qk_bf, vt_bf, aout_bf);

    // 3) output projection (fp32 out + bias); 128^2 tile, 512 blocks
    gemm_nt_mfma<0><<<dim3(M / 128, DIM / 128), 256, 0, stream>>>(
        aout_bf, wproj_bf, b_proj, out, nullptr, M, DIM, DIM);
}